// Round 5
// baseline (407.000 us; speedup 1.0000x reference)
//
#include <hip/hip_runtime.h>

// ShallowSIRENWithPosEmb — fp16 3-term MFMA version.
// W = Wh + Wl*2^-10 (fp16, Wl pre-scaled x2^10); X = Xh + Xl*2^-10 (fp16, Xl pre-scaled x2^10).
// D ~= Wh*Xh + Wl'*(Xh*2^-10) + Wh*(Xl'*2^-10)  via 3x mfma_f32_32x32x16_f16, fp32 accum.
// 128 pts/block, 512 thr (8 waves = 4 ow x 2 pw), each wave 2 o-tiles x 2 pt-tiles.
// LDS: lXh 64KB + lXl 64KB (swizzled [pt][256 fp16]) + lW 16KB slab = 144KB -> 1 block/CU.

#define SCALE_F 8.333333333333334f   // 2/0.24

typedef _Float16 hf;
typedef __attribute__((ext_vector_type(8)))  _Float16 hf8;
typedef __attribute__((ext_vector_type(16))) float f32x16;

// ---- Cody-Waite sin/cos in radians (embeds: args up to ~2e4, matches fp32 ref rounding) ----
__device__ __forceinline__ float redrev(float x) {
  const float chi = 0.15915494309189535f;
  const float clo = 6.4206383e-09f;
  float n = rintf(x * chi);
  float d = __builtin_fmaf(x, chi, -n);
  return __builtin_fmaf(x, clo, d);
}
__device__ __forceinline__ float fsin(float x) { return __builtin_amdgcn_sinf(redrev(x)); }
__device__ __forceinline__ float fcos(float x) { return __builtin_amdgcn_cosf(redrev(x)); }
// ---- rev-space sin for film (freq/2pi folded into the fma) ----
__device__ __forceinline__ float sinrev(float t) { return __builtin_amdgcn_sinf(t - rintf(t)); }

#define INV2PI 0.15915494309189535f
#define C15R   2.3873241463784303f   // 15/(2pi)
#define C30R   4.7746482927568605f   // 30/(2pi)

__device__ __forceinline__ unsigned pk2h(hf a, hf b) {
  return ((unsigned)__builtin_bit_cast(unsigned short, a)) |
         (((unsigned)__builtin_bit_cast(unsigned short, b)) << 16);
}
// ushort index of a 16B slot in an lX plane, XOR-swizzled by point
__device__ __forceinline__ int swadr(int pt, int slot) {
  return pt * 256 + ((slot ^ (pt & 7)) << 3);
}

// ---- weight prep: fp16 hi + (lo*2^10), MFMA slab order ----
// slab (per kstep, 8192 ushort = 16KB): [hi:4096][lo:4096]; within: [ot:8][kh:2][o5:32][j:8]
// L1 base 0 (4 slabs, K=64 pad); L2 base 32768 (16); L3 base 163840 (18, K=[x2(256)|de(27)pad(5)])
__global__ void prep_w(const float* __restrict__ W1, const float* __restrict__ W2,
                       const float* __restrict__ Wcs, unsigned short* __restrict__ wsu)
{
  int t = blockIdx.x * 256 + threadIdx.x;
  if (t >= 155648) return;
  int L, pos, base;
  if (t < 16384)      { L = 0; pos = t;         base = 0; }
  else if (t < 81920) { L = 1; pos = t - 16384; base = 32768; }
  else                { L = 2; pos = t - 81920; base = 163840; }
  int kstep = pos >> 12, r = pos & 4095;
  int ot = (r >> 9) & 7, kh = (r >> 8) & 1, o5 = (r >> 3) & 31, j = r & 7;
  int o = ot * 32 + o5, k = kstep * 16 + kh * 8 + j;
  float wv = 0.f;
  if (L == 0)      { if (k < 63) wv = W1[o * 63 + k]; }
  else if (L == 1) { wv = W2[o * 256 + k]; }
  else { if (k < 256) wv = Wcs[o * 283 + 27 + k];
         else { int q = k - 256; if (q < 27) wv = Wcs[o * 283 + q]; } }
  hf hh = (hf)wv;
  hf ll = (hf)((wv - (float)hh) * 1024.0f);   // scaled lo term (stays fp16-normal)
  wsu[base + kstep * 8192 + r]        = __builtin_bit_cast(unsigned short, hh);
  wsu[base + kstep * 8192 + 4096 + r] = __builtin_bit_cast(unsigned short, ll);
}

__device__ __forceinline__ float peval(float x0, float x1, float x2, int k) {
  if (k >= 63) return 0.f;
  if (k < 3) return (k == 0) ? x0 : ((k == 1) ? x1 : x2);
  int rr = k - 3, f = rr / 6, rem = rr - f * 6;
  int d = (rem < 3) ? rem : rem - 3;
  float xa = (d == 0) ? x0 : ((d == 1) ? x1 : x2);
  float arg = xa * (float)(1 << f);
  return (rem < 3) ? fsin(arg) : fcos(arg);
}
__device__ __forceinline__ float deval(float r0, float r1, float r2, int k) {
  if (k >= 27) return 0.f;
  if (k < 3) return (k == 0) ? r0 : ((k == 1) ? r1 : r2);
  int rr = k - 3, f = rr / 6, rem = rr - f * 6;
  int d = (rem < 3) ? rem : rem - 3;
  float ra = (d == 0) ? r0 : ((d == 1) ? r1 : r2);
  float arg = ra * (float)(1 << f);
  return (rem < 3) ? fsin(arg) : fcos(arg);
}

// ---- one layer's MFMA loop; last 2 ksteps take B from de regs when DE ----
// deB layout: [ (ks_local)*2 + (0=hi,1=lo-scaled) ][ pt 0/1 ] flattened: deB[ksl][plane][pt]
template <int NK, bool DE>
__device__ __forceinline__ void layer_loop(
    const unsigned short* __restrict__ prep,
    unsigned short* __restrict__ lW, const unsigned short* __restrict__ lX,
    f32x16 acc[2][2], int tid, int ow, int ptA, int ptB, int h, int l31,
    const hf8* deBh, const hf8* deBl)   // 4 each: [ksl*2 + pt] (valid when DE)
{
  { // stage slab 0 (barrier also orders prior-phase lX stores)
    const float4* s0 = (const float4*)prep;
    ((float4*)lW)[tid] = s0[tid];
    ((float4*)lW)[tid + 512] = s0[tid + 512];
  }
  __syncthreads();
  #pragma unroll 1
  for (int ks = 0; ks < NK; ++ks) {
    float4 pf0, pf1;
    const bool pre = (ks + 1) < NK;
    if (pre) {   // register prefetch of next slab, hidden under MFMAs
      const float4* s = (const float4*)(prep + (size_t)(ks + 1) * 8192);
      pf0 = s[tid]; pf1 = s[tid + 512];
    }
    hf8 Bh0, Bh1, Bl0, Bl1;
    if (!DE || ks < NK - 2) {
      Bh0 = *(const hf8*)&lX[swadr(ptA, ks * 2 + h)];
      Bh1 = *(const hf8*)&lX[swadr(ptB, ks * 2 + h)];
      Bl0 = *(const hf8*)&lX[32768 + swadr(ptA, ks * 2 + h)];
      Bl1 = *(const hf8*)&lX[32768 + swadr(ptB, ks * 2 + h)];
    } else {
      int ksl = ks - (NK - 2);
      Bh0 = deBh[ksl * 2 + 0]; Bh1 = deBh[ksl * 2 + 1];
      Bl0 = deBl[ksl * 2 + 0]; Bl1 = deBl[ksl * 2 + 1];
    }
    const hf sc = (hf)0.0009765625f;          // 2^-10, exact
    hf8 Bh0s = Bh0 * sc, Bh1s = Bh1 * sc;     // for Wl term
    hf8 Bl0s = Bl0 * sc, Bl1s = Bl1 * sc;     // un-scale X residual
    #pragma unroll
    for (int oi = 0; oi < 2; ++oi) {
      const int wb = (ow * 2 + oi) * 512 + h * 256 + l31 * 8;
      hf8 Ah = *(const hf8*)&lW[wb];
      hf8 Al = *(const hf8*)&lW[4096 + wb];
      acc[oi][0] = __builtin_amdgcn_mfma_f32_32x32x16_f16(Ah, Bh0,  acc[oi][0], 0, 0, 0);
      acc[oi][0] = __builtin_amdgcn_mfma_f32_32x32x16_f16(Al, Bh0s, acc[oi][0], 0, 0, 0);
      acc[oi][0] = __builtin_amdgcn_mfma_f32_32x32x16_f16(Ah, Bl0s, acc[oi][0], 0, 0, 0);
      acc[oi][1] = __builtin_amdgcn_mfma_f32_32x32x16_f16(Ah, Bh1,  acc[oi][1], 0, 0, 0);
      acc[oi][1] = __builtin_amdgcn_mfma_f32_32x32x16_f16(Al, Bh1s, acc[oi][1], 0, 0, 0);
      acc[oi][1] = __builtin_amdgcn_mfma_f32_32x32x16_f16(Ah, Bl1s, acc[oi][1], 0, 0, 0);
    }
    __syncthreads();
    if (pre) { ((float4*)lW)[tid] = pf0; ((float4*)lW)[tid + 512] = pf1; }
    __syncthreads();
  }
}

// store 4 values to both X planes (hi + scaled residual), 8B packed writes each
__device__ __forceinline__ void store_pair(unsigned short* lX, int pt, int slot, int off,
                                           float v0, float v1, float v2, float v3)
{
  hf h0 = (hf)v0, h1 = (hf)v1, h2 = (hf)v2, h3 = (hf)v3;
  int base = pt * 256 + ((slot ^ (pt & 7)) << 3) + off;
  *(uint2*)&lX[base] = make_uint2(pk2h(h0, h1), pk2h(h2, h3));
  hf r0 = (hf)((v0 - (float)h0) * 1024.f), r1 = (hf)((v1 - (float)h1) * 1024.f);
  hf r2 = (hf)((v2 - (float)h2) * 1024.f), r3 = (hf)((v3 - (float)h3) * 1024.f);
  *(uint2*)&lX[32768 + base] = make_uint2(pk2h(r0, r1), pk2h(r2, r3));
}

__global__ void __launch_bounds__(512, 1)
siren_mfma(const float* __restrict__ input, const float* __restrict__ rdir,
           const float* __restrict__ sn, const float* __restrict__ sc,
           const float* __restrict__ b1, const float* __restrict__ b2,
           const float* __restrict__ Wf, const float* __restrict__ bfp,
           const float* __restrict__ bcs, const float* __restrict__ Wcl,
           const float* __restrict__ bcl, const unsigned short* __restrict__ wsu,
           float* __restrict__ out)
{
  __shared__ __align__(16) unsigned char smem[147456];   // 144KB -> 1 block/CU
  unsigned short* lX = (unsigned short*)smem;            // 64KB hi + 64KB lo planes
  unsigned short* lW = (unsigned short*)(smem + 131072); // 16KB slab
  float* lP = (float*)smem;                              // epilogue alias over lX

  const int tid = threadIdx.x;
  const int w = tid >> 6, l = tid & 63;
  const int ow = w >> 1, pw = w & 1;
  const int l31 = l & 31, h = l >> 5;
  const int gpt0 = blockIdx.x << 7;
  const int b = blockIdx.x >> 9;                         // 512 blocks per batch
  const int ptA = pw * 64 + l31, ptB = ptA + 32;
  const float* snb = sn + b * 1024;
  const float* scb = sc + b * 512;

  // pinned ray dirs for the two points this lane serves
  float rA0, rA1, rA2, rB0, rB1, rB2;
  {
    const float* rp = rdir + (size_t)(gpt0 + ptA) * 3;
    rA0 = rp[0]; rA1 = rp[1]; rA2 = rp[2];
    const float* rq = rdir + (size_t)(gpt0 + ptB) * 3;
    rB0 = rq[0]; rB1 = rq[1]; rB2 = rq[2];
  }

  // ---- embed phase: pe (K=64, k=63 pad) -> both lX planes ----
  {
    const int ept = tid & 127, eseg = tid >> 7;
    const float* ip = input + (size_t)(gpt0 + ept) * 3;
    float x0 = ip[0] * SCALE_F, x1 = ip[1] * SCALE_F, x2 = ip[2] * SCALE_F;
    #pragma unroll
    for (int j = 0; j < 4; ++j) {          // 4 quads of k per segment
      int k0 = eseg * 16 + 4 * j;
      float v0 = peval(x0, x1, x2, k0),     v1 = peval(x0, x1, x2, k0 + 1);
      float v2 = peval(x0, x1, x2, k0 + 2), v3 = peval(x0, x1, x2, k0 + 3);
      int slot = eseg * 2 + (j >> 1);
      store_pair(lX, ept, slot, (j & 1) * 4, v0, v1, v2, v3);
    }
  }
  __syncthreads();

  f32x16 acc[2][2];
  float sp0 = 0.f, sp1 = 0.f;

  // ================= layer 1: pe(64) -> x1 =================
  #pragma unroll
  for (int oi = 0; oi < 2; ++oi)
    #pragma unroll
    for (int q = 0; q < 4; ++q) {
      int o0 = ow * 64 + oi * 32 + q * 8 + h * 4;
      float4 bv = *(const float4*)&b1[o0];
      acc[oi][0][q*4+0] = bv.x; acc[oi][0][q*4+1] = bv.y; acc[oi][0][q*4+2] = bv.z; acc[oi][0][q*4+3] = bv.w;
      acc[oi][1][q*4+0] = bv.x; acc[oi][1][q*4+1] = bv.y; acc[oi][1][q*4+2] = bv.z; acc[oi][1][q*4+3] = bv.w;
    }
  layer_loop<4, false>(wsu, lW, lX, acc, tid, ow, ptA, ptB, h, l31, nullptr, nullptr);
  #pragma unroll
  for (int oi = 0; oi < 2; ++oi)
    #pragma unroll
    for (int q = 0; q < 4; ++q) {
      int o0 = ow * 64 + oi * 32 + q * 8 + h * 4;
      float4 f4 = *(const float4*)&snb[o0];
      float4 p4 = *(const float4*)&snb[512 + o0];
      float fr0 = __builtin_fmaf(f4.x, C15R, C30R), fr1 = __builtin_fmaf(f4.y, C15R, C30R);
      float fr2 = __builtin_fmaf(f4.z, C15R, C30R), fr3 = __builtin_fmaf(f4.w, C15R, C30R);
      float pr0 = p4.x * INV2PI, pr1 = p4.y * INV2PI, pr2 = p4.z * INV2PI, pr3 = p4.w * INV2PI;
      int slot = ow * 8 + oi * 4 + q;
      #pragma unroll
      for (int pi = 0; pi < 2; ++pi) {
        float v0 = sinrev(__builtin_fmaf(fr0, acc[oi][pi][q*4+0], pr0));
        float v1 = sinrev(__builtin_fmaf(fr1, acc[oi][pi][q*4+1], pr1));
        float v2 = sinrev(__builtin_fmaf(fr2, acc[oi][pi][q*4+2], pr2));
        float v3 = sinrev(__builtin_fmaf(fr3, acc[oi][pi][q*4+3], pr3));
        int pt = (pi == 0) ? ptA : ptB;
        store_pair(lX, pt, slot, h * 4, v0, v1, v2, v3);
      }
    }

  // ================= layer 2: x1 -> x2, sigma =================
  #pragma unroll
  for (int oi = 0; oi < 2; ++oi)
    #pragma unroll
    for (int q = 0; q < 4; ++q) {
      int o0 = ow * 64 + oi * 32 + q * 8 + h * 4;
      float4 bv = *(const float4*)&b2[o0];
      acc[oi][0][q*4+0] = bv.x; acc[oi][0][q*4+1] = bv.y; acc[oi][0][q*4+2] = bv.z; acc[oi][0][q*4+3] = bv.w;
      acc[oi][1][q*4+0] = bv.x; acc[oi][1][q*4+1] = bv.y; acc[oi][1][q*4+2] = bv.z; acc[oi][1][q*4+3] = bv.w;
    }
  layer_loop<16, false>(wsu + 32768, lW, lX, acc, tid, ow, ptA, ptB, h, l31, nullptr, nullptr);
  #pragma unroll
  for (int oi = 0; oi < 2; ++oi)
    #pragma unroll
    for (int q = 0; q < 4; ++q) {
      int o0 = ow * 64 + oi * 32 + q * 8 + h * 4;
      float4 f4 = *(const float4*)&snb[256 + o0];
      float4 p4 = *(const float4*)&snb[768 + o0];
      float4 wf = *(const float4*)&Wf[o0];
      float fr0 = __builtin_fmaf(f4.x, C15R, C30R), fr1 = __builtin_fmaf(f4.y, C15R, C30R);
      float fr2 = __builtin_fmaf(f4.z, C15R, C30R), fr3 = __builtin_fmaf(f4.w, C15R, C30R);
      float pr0 = p4.x * INV2PI, pr1 = p4.y * INV2PI, pr2 = p4.z * INV2PI, pr3 = p4.w * INV2PI;
      int slot = ow * 8 + oi * 4 + q;
      #pragma unroll
      for (int pi = 0; pi < 2; ++pi) {
        float v0 = sinrev(__builtin_fmaf(fr0, acc[oi][pi][q*4+0], pr0));
        float v1 = sinrev(__builtin_fmaf(fr1, acc[oi][pi][q*4+1], pr1));
        float v2 = sinrev(__builtin_fmaf(fr2, acc[oi][pi][q*4+2], pr2));
        float v3 = sinrev(__builtin_fmaf(fr3, acc[oi][pi][q*4+3], pr3));
        float s = __builtin_fmaf(wf.x, v0, __builtin_fmaf(wf.y, v1,
                  __builtin_fmaf(wf.z, v2, wf.w * v3)));
        if (pi == 0) sp0 += s; else sp1 += s;
        int pt = (pi == 0) ? ptA : ptB;
        store_pair(lX, pt, slot, h * 4, v0, v1, v2, v3);
      }
    }

  // ---- build de B-frags (hi + scaled residual) in registers ----
  hf8 deBh[4], deBl[4];
  #pragma unroll
  for (int ksl = 0; ksl < 2; ++ksl)
    #pragma unroll
    for (int pi = 0; pi < 2; ++pi) {
      float r0 = (pi == 0) ? rA0 : rB0, r1 = (pi == 0) ? rA1 : rB1, r2 = (pi == 0) ? rA2 : rB2;
      unsigned uh[4], ul[4];
      #pragma unroll
      for (int jj = 0; jj < 4; ++jj) {
        int k = ksl * 16 + h * 8 + 2 * jj;
        float va = deval(r0, r1, r2, k), vb = deval(r0, r1, r2, k + 1);
        hf ha = (hf)va, hb = (hf)vb;
        uh[jj] = pk2h(ha, hb);
        ul[jj] = pk2h((hf)((va - (float)ha) * 1024.f), (hf)((vb - (float)hb) * 1024.f));
      }
      uint4 vh = make_uint4(uh[0], uh[1], uh[2], uh[3]);
      uint4 vl = make_uint4(ul[0], ul[1], ul[2], ul[3]);
      deBh[ksl * 2 + pi] = __builtin_bit_cast(hf8, vh);
      deBl[ksl * 2 + pi] = __builtin_bit_cast(hf8, vl);
    }

  // ================= layer 3: [x2(256)|de(32)] -> hc, rgb =================
  #pragma unroll
  for (int oi = 0; oi < 2; ++oi)
    #pragma unroll
    for (int q = 0; q < 4; ++q) {
      int o0 = ow * 64 + oi * 32 + q * 8 + h * 4;
      float4 bv = *(const float4*)&bcs[o0];
      acc[oi][0][q*4+0] = bv.x; acc[oi][0][q*4+1] = bv.y; acc[oi][0][q*4+2] = bv.z; acc[oi][0][q*4+3] = bv.w;
      acc[oi][1][q*4+0] = bv.x; acc[oi][1][q*4+1] = bv.y; acc[oi][1][q*4+2] = bv.z; acc[oi][1][q*4+3] = bv.w;
    }
  layer_loop<18, true>(wsu + 163840, lW, lX, acc, tid, ow, ptA, ptB, h, l31, deBh, deBl);
  float q00 = 0.f, q01 = 0.f, q02 = 0.f, q10 = 0.f, q11 = 0.f, q12 = 0.f;
  #pragma unroll
  for (int oi = 0; oi < 2; ++oi)
    #pragma unroll
    for (int q = 0; q < 4; ++q) {
      int o0 = ow * 64 + oi * 32 + q * 8 + h * 4;
      float4 f4 = *(const float4*)&scb[o0];
      float4 p4 = *(const float4*)&scb[256 + o0];
      float4 w0 = *(const float4*)&Wcl[o0];
      float4 w1 = *(const float4*)&Wcl[256 + o0];
      float4 w2 = *(const float4*)&Wcl[512 + o0];
      float fr0 = __builtin_fmaf(f4.x, C15R, C30R), fr1 = __builtin_fmaf(f4.y, C15R, C30R);
      float fr2 = __builtin_fmaf(f4.z, C15R, C30R), fr3 = __builtin_fmaf(f4.w, C15R, C30R);
      float pr0 = p4.x * INV2PI, pr1 = p4.y * INV2PI, pr2 = p4.z * INV2PI, pr3 = p4.w * INV2PI;
      #pragma unroll
      for (int pi = 0; pi < 2; ++pi) {
        float v0 = sinrev(__builtin_fmaf(fr0, acc[oi][pi][q*4+0], pr0));
        float v1 = sinrev(__builtin_fmaf(fr1, acc[oi][pi][q*4+1], pr1));
        float v2 = sinrev(__builtin_fmaf(fr2, acc[oi][pi][q*4+2], pr2));
        float v3 = sinrev(__builtin_fmaf(fr3, acc[oi][pi][q*4+3], pr3));
        float a0 = __builtin_fmaf(w0.x, v0, __builtin_fmaf(w0.y, v1, __builtin_fmaf(w0.z, v2, w0.w * v3)));
        float a1 = __builtin_fmaf(w1.x, v0, __builtin_fmaf(w1.y, v1, __builtin_fmaf(w1.z, v2, w1.w * v3)));
        float a2 = __builtin_fmaf(w2.x, v0, __builtin_fmaf(w2.y, v1, __builtin_fmaf(w2.z, v2, w2.w * v3)));
        if (pi == 0) { q00 += a0; q01 += a1; q02 += a2; }
        else         { q10 += a0; q11 += a1; q12 += a2; }
      }
    }

  // combine h halves within wave, then publish per-wave partials
  q00 += __shfl_xor(q00, 32); q01 += __shfl_xor(q01, 32); q02 += __shfl_xor(q02, 32);
  q10 += __shfl_xor(q10, 32); q11 += __shfl_xor(q11, 32); q12 += __shfl_xor(q12, 32);
  sp0 += __shfl_xor(sp0, 32); sp1 += __shfl_xor(sp1, 32);
  if (h == 0) {   // lX fully consumed; lP aliases it
    *(float4*)&lP[((w * 2 + 0) * 32 + l31) * 4] = make_float4(q00, q01, q02, sp0);
    *(float4*)&lP[((w * 2 + 1) * 32 + l31) * 4] = make_float4(q10, q11, q12, sp1);
  }
  __syncthreads();

  // ---- epilogue: sum the 4 ow waves, add bias, store ----
  {
    int ptL = tid >> 2, ch = tid & 3;
    int pwt = ptL >> 6, pit = (ptL >> 5) & 1, lt = ptL & 31;
    float v = 0.f;
    #pragma unroll
    for (int owt = 0; owt < 4; ++owt) {
      int wv_ = (owt * 2 + pwt);
      v += lP[((wv_ * 2 + pit) * 32 + lt) * 4 + ch];
    }
    v += (ch == 3) ? bfp[0] : bcl[ch];
    out[((size_t)gpt0 + ptL) * 4 + ch] = v;
  }
}

extern "C" void kernel_launch(void* const* d_in, const int* in_sizes, int n_in,
                              void* d_out, int out_size, void* d_ws, size_t ws_size,
                              hipStream_t stream) {
  const float* input = (const float*)d_in[0];
  const float* rdir  = (const float*)d_in[1];
  const float* sn    = (const float*)d_in[2];
  const float* sc    = (const float*)d_in[3];
  const float* W1    = (const float*)d_in[4];
  const float* b1    = (const float*)d_in[5];
  const float* W2    = (const float*)d_in[6];
  const float* b2    = (const float*)d_in[7];
  const float* Wf    = (const float*)d_in[8];
  const float* bf    = (const float*)d_in[9];
  const float* Wcs   = (const float*)d_in[10];
  const float* bcs   = (const float*)d_in[11];
  const float* Wcl   = (const float*)d_in[12];
  const float* bcl   = (const float*)d_in[13];
  unsigned short* wsu = (unsigned short*)d_ws;
  float* out = (float*)d_out;

  prep_w<<<608, 256, 0, stream>>>(W1, W2, Wcs, wsu);
  siren_mfma<<<2048, 512, 0, stream>>>(input, rdir, sn, sc, b1, b2, Wf, bf,
                                       bcs, Wcl, bcl, wsu, out);
}

// Round 6
// 320.823 us; speedup vs baseline: 1.2686x; 1.2686x over previous
//
#include <hip/hip_runtime.h>

// ShallowSIRENWithPosEmb — fp16 3-term MFMA + async weight-slab pipeline.
// W = Wh + Wl*2^-10 (fp16, Wl pre-scaled); X = Xh + Xl*2^-10 (fp16, Xl pre-scaled).
// D ~= Wh*Xh + Wl'*(Xh*2^-10) + Wh*(Xl'*2^-10) via 3x mfma_f32_32x32x16_f16, fp32 accum.
// 128 pts/block, 512 thr (8 waves = 4 ow x 2 pw). Weight slabs staged with
// global_load_lds, 2-deep double-buffer, counted vmcnt(2) (never 0 in main loop).
// LDS: lX 128KB (2 fp16 planes) + 2x16KB slab dbuf = 160KB exactly.

#define SCALE_F 8.333333333333334f   // 2/0.24

typedef _Float16 hf;
typedef __attribute__((ext_vector_type(8)))  _Float16 hf8;
typedef __attribute__((ext_vector_type(16))) float f32x16;

// ---- Cody-Waite sin/cos in radians (embeds: args up to ~2e4) ----
__device__ __forceinline__ float redrev(float x) {
  const float chi = 0.15915494309189535f;
  const float clo = 6.4206383e-09f;
  float n = rintf(x * chi);
  float d = __builtin_fmaf(x, chi, -n);
  return __builtin_fmaf(x, clo, d);
}
__device__ __forceinline__ float fsin(float x) { return __builtin_amdgcn_sinf(redrev(x)); }
__device__ __forceinline__ float fcos(float x) { return __builtin_amdgcn_cosf(redrev(x)); }
// rev-space sin for film (freq/2pi folded into the fma)
__device__ __forceinline__ float sinrev(float t) { return __builtin_amdgcn_sinf(t - rintf(t)); }

#define INV2PI 0.15915494309189535f
#define C15R   2.3873241463784303f   // 15/(2pi)
#define C30R   4.7746482927568605f   // 30/(2pi)

__device__ __forceinline__ unsigned pk2h(hf a, hf b) {
  return ((unsigned)__builtin_bit_cast(unsigned short, a)) |
         (((unsigned)__builtin_bit_cast(unsigned short, b)) << 16);
}

// ---- weight prep: fp16 hi + (lo*2^10), MFMA slab order ----
// slab (per kstep, 8192 ushort = 16KB): [hi:4096][lo:4096]; within: [ot:8][kh:2][o5:32][j:8]
// L1 base 0 (4 slabs, K=64 pad); L2 base 32768 (16); L3 base 163840 (18, K=[x2(256)|de(27)pad(5)])
__global__ void prep_w(const float* __restrict__ W1, const float* __restrict__ W2,
                       const float* __restrict__ Wcs, unsigned short* __restrict__ wsu)
{
  int t = blockIdx.x * 256 + threadIdx.x;
  if (t >= 155648) return;
  int L, pos, base;
  if (t < 16384)      { L = 0; pos = t;         base = 0; }
  else if (t < 81920) { L = 1; pos = t - 16384; base = 32768; }
  else                { L = 2; pos = t - 81920; base = 163840; }
  int kstep = pos >> 12, r = pos & 4095;
  int ot = (r >> 9) & 7, kh = (r >> 8) & 1, o5 = (r >> 3) & 31, j = r & 7;
  int o = ot * 32 + o5, k = kstep * 16 + kh * 8 + j;
  float wv = 0.f;
  if (L == 0)      { if (k < 63) wv = W1[o * 63 + k]; }
  else if (L == 1) { wv = W2[o * 256 + k]; }
  else { if (k < 256) wv = Wcs[o * 283 + 27 + k];
         else { int q = k - 256; if (q < 27) wv = Wcs[o * 283 + q]; } }
  hf hh = (hf)wv;
  hf ll = (hf)((wv - (float)hh) * 1024.0f);
  wsu[base + kstep * 8192 + r]        = __builtin_bit_cast(unsigned short, hh);
  wsu[base + kstep * 8192 + 4096 + r] = __builtin_bit_cast(unsigned short, ll);
}

__device__ __forceinline__ float peval(float x0, float x1, float x2, int k) {
  if (k >= 63) return 0.f;
  if (k < 3) return (k == 0) ? x0 : ((k == 1) ? x1 : x2);
  int rr = k - 3, f = rr / 6, rem = rr - f * 6;
  int d = (rem < 3) ? rem : rem - 3;
  float xa = (d == 0) ? x0 : ((d == 1) ? x1 : x2);
  float arg = xa * (float)(1 << f);
  return (rem < 3) ? fsin(arg) : fcos(arg);
}
__device__ __forceinline__ float deval(float r0, float r1, float r2, int k) {
  if (k >= 27) return 0.f;
  if (k < 3) return (k == 0) ? r0 : ((k == 1) ? r1 : r2);
  int rr = k - 3, f = rr / 6, rem = rr - f * 6;
  int d = (rem < 3) ? rem : rem - 3;
  float ra = (d == 0) ? r0 : ((d == 1) ? r1 : r2);
  float arg = ra * (float)(1 << f);
  return (rem < 3) ? fsin(arg) : fcos(arg);
}
__device__ __forceinline__ void build_de(float r0, float r1, float r2, int kbase,
                                         hf8& hh, hf8& ll) {
  unsigned uh[4], ul[4];
  #pragma unroll
  for (int jj = 0; jj < 4; ++jj) {
    float va = deval(r0, r1, r2, kbase + 2 * jj), vb = deval(r0, r1, r2, kbase + 2 * jj + 1);
    hf ha = (hf)va, hb = (hf)vb;
    uh[jj] = pk2h(ha, hb);
    ul[jj] = pk2h((hf)((va - (float)ha) * 1024.f), (hf)((vb - (float)hb) * 1024.f));
  }
  uint4 vh = make_uint4(uh[0], uh[1], uh[2], uh[3]);
  uint4 vl = make_uint4(ul[0], ul[1], ul[2], ul[3]);
  hh = __builtin_bit_cast(hf8, vh);
  ll = __builtin_bit_cast(hf8, vl);
}

// ---- async stage of one 16KB slab into lW buffer (per-wave 2KB chunk, 2 issues) ----
__device__ __forceinline__ void stage_slab(const unsigned short* __restrict__ prep, int ks,
                                           unsigned short* lWb, int wv, int lane) {
  const char* src = (const char*)prep + (size_t)ks * 16384 + wv * 2048 + lane * 16;
  char* dst = (char*)lWb + wv * 2048;            // wave-uniform base; HW adds lane*16
  __builtin_amdgcn_global_load_lds((const unsigned int*)src, (unsigned int*)dst, 16, 0, 0);
  __builtin_amdgcn_global_load_lds((const unsigned int*)(src + 1024),
                                   (unsigned int*)(dst + 1024), 16, 0, 0);
}

// ---- one kstep's 12 MFMAs (2 o-tiles x 2 pt-tiles x 3 terms) ----
__device__ __forceinline__ void kstep_mfma(const unsigned short* lwb, int wbA,
                                           hf8 Bh0, hf8 Bh1, hf8 Bl0, hf8 Bl1,
                                           f32x16& a00, f32x16& a01,
                                           f32x16& a10, f32x16& a11) {
  const hf sc = (hf)0.0009765625f;               // 2^-10, exact
  hf8 Bh0s = Bh0 * sc, Bh1s = Bh1 * sc, Bl0s = Bl0 * sc, Bl1s = Bl1 * sc;
  hf8 Ah0 = *(const hf8*)&lwb[wbA];
  hf8 Al0 = *(const hf8*)&lwb[4096 + wbA];
  hf8 Ah1 = *(const hf8*)&lwb[wbA + 512];
  hf8 Al1 = *(const hf8*)&lwb[4096 + wbA + 512];
  a00 = __builtin_amdgcn_mfma_f32_32x32x16_f16(Ah0, Bh0,  a00, 0, 0, 0);
  a00 = __builtin_amdgcn_mfma_f32_32x32x16_f16(Al0, Bh0s, a00, 0, 0, 0);
  a00 = __builtin_amdgcn_mfma_f32_32x32x16_f16(Ah0, Bl0s, a00, 0, 0, 0);
  a01 = __builtin_amdgcn_mfma_f32_32x32x16_f16(Ah0, Bh1,  a01, 0, 0, 0);
  a01 = __builtin_amdgcn_mfma_f32_32x32x16_f16(Al0, Bh1s, a01, 0, 0, 0);
  a01 = __builtin_amdgcn_mfma_f32_32x32x16_f16(Ah0, Bl1s, a01, 0, 0, 0);
  a10 = __builtin_amdgcn_mfma_f32_32x32x16_f16(Ah1, Bh0,  a10, 0, 0, 0);
  a10 = __builtin_amdgcn_mfma_f32_32x32x16_f16(Al1, Bh0s, a10, 0, 0, 0);
  a10 = __builtin_amdgcn_mfma_f32_32x32x16_f16(Ah1, Bl0s, a10, 0, 0, 0);
  a11 = __builtin_amdgcn_mfma_f32_32x32x16_f16(Ah1, Bh1,  a11, 0, 0, 0);
  a11 = __builtin_amdgcn_mfma_f32_32x32x16_f16(Al1, Bh1s, a11, 0, 0, 0);
  a11 = __builtin_amdgcn_mfma_f32_32x32x16_f16(Ah1, Bl1s, a11, 0, 0, 0);
}

// ---- one layer: NLX lX-ksteps (runtime loop) + (NKTOT-NLX) static de-ksteps ----
template <int NKTOT, int NLX>
__device__ __forceinline__ void layer_loop(
    const unsigned short* __restrict__ prep, unsigned short* lW,
    const unsigned short* lX, int ptA, int ptB, int h, int wbA, int wv, int lane,
    f32x16& a00, f32x16& a01, f32x16& a10, f32x16& a11,
    hf8 dhA0, hf8 dhB0, hf8 dhA1, hf8 dhB1,
    hf8 dlA0, hf8 dlB0, hf8 dlA1, hf8 dlB1)
{
  stage_slab(prep, 0, lW, wv, lane);
  if (NKTOT > 1) stage_slab(prep, 1, lW + 8192, wv, lane);
  const int bA = ptA * 256, bB = ptB * 256, sA = ptA & 7, sB = ptB & 7;
  #pragma unroll 1
  for (int ks = 0; ks < NLX; ++ks) {
    if (ks + 1 < NKTOT) asm volatile("s_waitcnt vmcnt(2)" ::: "memory");
    else                asm volatile("s_waitcnt vmcnt(0)" ::: "memory");
    __syncthreads();                       // slab ks in LDS for all waves; lX stores ordered
    int slot = ks * 2 + h;
    hf8 Bh0 = *(const hf8*)&lX[bA + ((slot ^ sA) << 3)];
    hf8 Bh1 = *(const hf8*)&lX[bB + ((slot ^ sB) << 3)];
    hf8 Bl0 = *(const hf8*)&lX[32768 + bA + ((slot ^ sA) << 3)];
    hf8 Bl1 = *(const hf8*)&lX[32768 + bB + ((slot ^ sB) << 3)];
    kstep_mfma(lW + (ks & 1) * 8192, wbA, Bh0, Bh1, Bl0, Bl1, a00, a01, a10, a11);
    __syncthreads();                       // all waves done reading slab ks
    if (ks + 2 < NKTOT) stage_slab(prep, ks + 2, lW + (ks & 1) * 8192, wv, lane);
  }
  if (NLX < NKTOT) {                       // static de tail (2 ksteps, named frags)
    asm volatile("s_waitcnt vmcnt(2)" ::: "memory");
    __syncthreads();
    kstep_mfma(lW + (NLX & 1) * 8192, wbA, dhA0, dhB0, dlA0, dlB0, a00, a01, a10, a11);
    __syncthreads();
    asm volatile("s_waitcnt vmcnt(0)" ::: "memory");
    __syncthreads();
    kstep_mfma(lW + ((NLX + 1) & 1) * 8192, wbA, dhA1, dhB1, dlA1, dlB1, a00, a01, a10, a11);
    __syncthreads();
  }
}

// store 4 values to both X planes (hi + scaled residual), 8B packed writes each
__device__ __forceinline__ void store_pair(unsigned short* lX, int pt, int slot, int off,
                                           float v0, float v1, float v2, float v3)
{
  hf h0 = (hf)v0, h1 = (hf)v1, h2 = (hf)v2, h3 = (hf)v3;
  int base = pt * 256 + ((slot ^ (pt & 7)) << 3) + off;
  *(uint2*)&lX[base] = make_uint2(pk2h(h0, h1), pk2h(h2, h3));
  hf r0 = (hf)((v0 - (float)h0) * 1024.f), r1 = (hf)((v1 - (float)h1) * 1024.f);
  hf r2 = (hf)((v2 - (float)h2) * 1024.f), r3 = (hf)((v3 - (float)h3) * 1024.f);
  *(uint2*)&lX[32768 + base] = make_uint2(pk2h(r0, r1), pk2h(r2, r3));
}

__global__ void __launch_bounds__(512, 1)
siren_mfma(const float* __restrict__ input, const float* __restrict__ rdir,
           const float* __restrict__ sn, const float* __restrict__ sc,
           const float* __restrict__ b1, const float* __restrict__ b2,
           const float* __restrict__ Wf, const float* __restrict__ bfp,
           const float* __restrict__ bcs, const float* __restrict__ Wcl,
           const float* __restrict__ bcl, const unsigned short* __restrict__ wsu,
           float* __restrict__ out)
{
  __shared__ __align__(16) unsigned char smem[163840];   // 160KB exactly
  unsigned short* lX = (unsigned short*)smem;            // 64KB hi + 64KB lo
  unsigned short* lW = (unsigned short*)(smem + 131072); // 2 x 16KB slab dbuf
  float* lP = (float*)smem;                              // epilogue alias over lX

  const int tid = threadIdx.x;
  const int w = tid >> 6, lane = tid & 63;
  const int ow = w >> 1, pw = w & 1;
  const int l31 = lane & 31, h = lane >> 5;
  const int gpt0 = blockIdx.x << 7;
  const int b = blockIdx.x >> 9;                         // 512 blocks per batch
  const int ptA = pw * 64 + l31, ptB = ptA + 32;
  const int wbA = ow * 1024 + h * 256 + l31 * 8;         // A-frag base (oi=0); oi=1 at +512
  const float* snb = sn + b * 1024;
  const float* scb = sc + b * 512;

  float rA0, rA1, rA2, rB0, rB1, rB2;
  {
    const float* rp = rdir + (size_t)(gpt0 + ptA) * 3;
    rA0 = rp[0]; rA1 = rp[1]; rA2 = rp[2];
    const float* rq = rdir + (size_t)(gpt0 + ptB) * 3;
    rB0 = rq[0]; rB1 = rq[1]; rB2 = rq[2];
  }

  // ---- embed phase: pe (K=64, k=63 pad) -> both lX planes ----
  {
    const int ept = tid & 127, eseg = tid >> 7;
    const float* ip = input + (size_t)(gpt0 + ept) * 3;
    float x0 = ip[0] * SCALE_F, x1 = ip[1] * SCALE_F, x2 = ip[2] * SCALE_F;
    #pragma unroll
    for (int j = 0; j < 4; ++j) {
      int k0 = eseg * 16 + 4 * j;
      float v0 = peval(x0, x1, x2, k0),     v1 = peval(x0, x1, x2, k0 + 1);
      float v2 = peval(x0, x1, x2, k0 + 2), v3 = peval(x0, x1, x2, k0 + 3);
      int slot = eseg * 2 + (j >> 1);
      store_pair(lX, ept, slot, (j & 1) * 4, v0, v1, v2, v3);
    }
  }

  f32x16 a00, a01, a10, a11;
  hf8 hz = {};
  float sp0 = 0.f, sp1 = 0.f;

  // ================= layer 1: pe(64) -> x1 =================
  #pragma unroll
  for (int oi = 0; oi < 2; ++oi)
    #pragma unroll
    for (int q = 0; q < 4; ++q) {
      int o0 = ow * 64 + oi * 32 + q * 8 + h * 4;
      float4 bv = *(const float4*)&b1[o0];
      f32x16& aA = oi ? a10 : a00; f32x16& aB = oi ? a11 : a01;
      aA[q*4+0] = bv.x; aA[q*4+1] = bv.y; aA[q*4+2] = bv.z; aA[q*4+3] = bv.w;
      aB[q*4+0] = bv.x; aB[q*4+1] = bv.y; aB[q*4+2] = bv.z; aB[q*4+3] = bv.w;
    }
  layer_loop<4, 4>(wsu, lW, lX, ptA, ptB, h, wbA, w, lane, a00, a01, a10, a11,
                   hz, hz, hz, hz, hz, hz, hz, hz);
  #pragma unroll
  for (int oi = 0; oi < 2; ++oi)
    #pragma unroll
    for (int q = 0; q < 4; ++q) {
      int o0 = ow * 64 + oi * 32 + q * 8 + h * 4;
      float4 f4 = *(const float4*)&snb[o0];
      float4 p4 = *(const float4*)&snb[512 + o0];
      float fr0 = __builtin_fmaf(f4.x, C15R, C30R), fr1 = __builtin_fmaf(f4.y, C15R, C30R);
      float fr2 = __builtin_fmaf(f4.z, C15R, C30R), fr3 = __builtin_fmaf(f4.w, C15R, C30R);
      float pr0 = p4.x * INV2PI, pr1 = p4.y * INV2PI, pr2 = p4.z * INV2PI, pr3 = p4.w * INV2PI;
      int slot = ow * 8 + oi * 4 + q;
      #pragma unroll
      for (int pi = 0; pi < 2; ++pi) {
        const f32x16& a = pi ? (oi ? a11 : a01) : (oi ? a10 : a00);
        float v0 = sinrev(__builtin_fmaf(fr0, a[q*4+0], pr0));
        float v1 = sinrev(__builtin_fmaf(fr1, a[q*4+1], pr1));
        float v2 = sinrev(__builtin_fmaf(fr2, a[q*4+2], pr2));
        float v3 = sinrev(__builtin_fmaf(fr3, a[q*4+3], pr3));
        store_pair(lX, pi ? ptB : ptA, slot, h * 4, v0, v1, v2, v3);
      }
    }

  // ================= layer 2: x1 -> x2, sigma =================
  #pragma unroll
  for (int oi = 0; oi < 2; ++oi)
    #pragma unroll
    for (int q = 0; q < 4; ++q) {
      int o0 = ow * 64 + oi * 32 + q * 8 + h * 4;
      float4 bv = *(const float4*)&b2[o0];
      f32x16& aA = oi ? a10 : a00; f32x16& aB = oi ? a11 : a01;
      aA[q*4+0] = bv.x; aA[q*4+1] = bv.y; aA[q*4+2] = bv.z; aA[q*4+3] = bv.w;
      aB[q*4+0] = bv.x; aB[q*4+1] = bv.y; aB[q*4+2] = bv.z; aB[q*4+3] = bv.w;
    }
  layer_loop<16, 16>(wsu + 32768, lW, lX, ptA, ptB, h, wbA, w, lane, a00, a01, a10, a11,
                     hz, hz, hz, hz, hz, hz, hz, hz);
  #pragma unroll
  for (int oi = 0; oi < 2; ++oi)
    #pragma unroll
    for (int q = 0; q < 4; ++q) {
      int o0 = ow * 64 + oi * 32 + q * 8 + h * 4;
      float4 f4 = *(const float4*)&snb[256 + o0];
      float4 p4 = *(const float4*)&snb[768 + o0];
      float4 wf = *(const float4*)&Wf[o0];
      float fr0 = __builtin_fmaf(f4.x, C15R, C30R), fr1 = __builtin_fmaf(f4.y, C15R, C30R);
      float fr2 = __builtin_fmaf(f4.z, C15R, C30R), fr3 = __builtin_fmaf(f4.w, C15R, C30R);
      float pr0 = p4.x * INV2PI, pr1 = p4.y * INV2PI, pr2 = p4.z * INV2PI, pr3 = p4.w * INV2PI;
      int slot = ow * 8 + oi * 4 + q;
      #pragma unroll
      for (int pi = 0; pi < 2; ++pi) {
        const f32x16& a = pi ? (oi ? a11 : a01) : (oi ? a10 : a00);
        float v0 = sinrev(__builtin_fmaf(fr0, a[q*4+0], pr0));
        float v1 = sinrev(__builtin_fmaf(fr1, a[q*4+1], pr1));
        float v2 = sinrev(__builtin_fmaf(fr2, a[q*4+2], pr2));
        float v3 = sinrev(__builtin_fmaf(fr3, a[q*4+3], pr3));
        float s = __builtin_fmaf(wf.x, v0, __builtin_fmaf(wf.y, v1,
                  __builtin_fmaf(wf.z, v2, wf.w * v3)));
        if (pi == 0) sp0 += s; else sp1 += s;
        store_pair(lX, pi ? ptB : ptA, slot, h * 4, v0, v1, v2, v3);
      }
    }

  // ---- de B-frags in named registers (static — no scratch) ----
  hf8 dhA0, dhB0, dhA1, dhB1, dlA0, dlB0, dlA1, dlB1;
  build_de(rA0, rA1, rA2, 0 * 16 + h * 8, dhA0, dlA0);
  build_de(rB0, rB1, rB2, 0 * 16 + h * 8, dhB0, dlB0);
  build_de(rA0, rA1, rA2, 1 * 16 + h * 8, dhA1, dlA1);
  build_de(rB0, rB1, rB2, 1 * 16 + h * 8, dhB1, dlB1);

  // ================= layer 3: [x2(256)|de(32)] -> hc, rgb =================
  #pragma unroll
  for (int oi = 0; oi < 2; ++oi)
    #pragma unroll
    for (int q = 0; q < 4; ++q) {
      int o0 = ow * 64 + oi * 32 + q * 8 + h * 4;
      float4 bv = *(const float4*)&bcs[o0];
      f32x16& aA = oi ? a10 : a00; f32x16& aB = oi ? a11 : a01;
      aA[q*4+0] = bv.x; aA[q*4+1] = bv.y; aA[q*4+2] = bv.z; aA[q*4+3] = bv.w;
      aB[q*4+0] = bv.x; aB[q*4+1] = bv.y; aB[q*4+2] = bv.z; aB[q*4+3] = bv.w;
    }
  layer_loop<18, 16>(wsu + 163840, lW, lX, ptA, ptB, h, wbA, w, lane, a00, a01, a10, a11,
                     dhA0, dhB0, dhA1, dhB1, dlA0, dlB0, dlA1, dlB1);
  float q00 = 0.f, q01 = 0.f, q02 = 0.f, q10 = 0.f, q11 = 0.f, q12 = 0.f;
  #pragma unroll
  for (int oi = 0; oi < 2; ++oi)
    #pragma unroll
    for (int q = 0; q < 4; ++q) {
      int o0 = ow * 64 + oi * 32 + q * 8 + h * 4;
      float4 f4 = *(const float4*)&scb[o0];
      float4 p4 = *(const float4*)&scb[256 + o0];
      float4 w0 = *(const float4*)&Wcl[o0];
      float4 w1 = *(const float4*)&Wcl[256 + o0];
      float4 w2 = *(const float4*)&Wcl[512 + o0];
      float fr0 = __builtin_fmaf(f4.x, C15R, C30R), fr1 = __builtin_fmaf(f4.y, C15R, C30R);
      float fr2 = __builtin_fmaf(f4.z, C15R, C30R), fr3 = __builtin_fmaf(f4.w, C15R, C30R);
      float pr0 = p4.x * INV2PI, pr1 = p4.y * INV2PI, pr2 = p4.z * INV2PI, pr3 = p4.w * INV2PI;
      #pragma unroll
      for (int pi = 0; pi < 2; ++pi) {
        const f32x16& a = pi ? (oi ? a11 : a01) : (oi ? a10 : a00);
        float v0 = sinrev(__builtin_fmaf(fr0, a[q*4+0], pr0));
        float v1 = sinrev(__builtin_fmaf(fr1, a[q*4+1], pr1));
        float v2 = sinrev(__builtin_fmaf(fr2, a[q*4+2], pr2));
        float v3 = sinrev(__builtin_fmaf(fr3, a[q*4+3], pr3));
        float t0 = __builtin_fmaf(w0.x, v0, __builtin_fmaf(w0.y, v1, __builtin_fmaf(w0.z, v2, w0.w * v3)));
        float t1 = __builtin_fmaf(w1.x, v0, __builtin_fmaf(w1.y, v1, __builtin_fmaf(w1.z, v2, w1.w * v3)));
        float t2 = __builtin_fmaf(w2.x, v0, __builtin_fmaf(w2.y, v1, __builtin_fmaf(w2.z, v2, w2.w * v3)));
        if (pi == 0) { q00 += t0; q01 += t1; q02 += t2; }
        else         { q10 += t0; q11 += t1; q12 += t2; }
      }
    }

  // combine h halves within wave, then publish per-wave partials
  q00 += __shfl_xor(q00, 32); q01 += __shfl_xor(q01, 32); q02 += __shfl_xor(q02, 32);
  q10 += __shfl_xor(q10, 32); q11 += __shfl_xor(q11, 32); q12 += __shfl_xor(q12, 32);
  sp0 += __shfl_xor(sp0, 32); sp1 += __shfl_xor(sp1, 32);
  if (h == 0) {   // lX fully consumed; lP aliases it
    *(float4*)&lP[((w * 2 + 0) * 32 + l31) * 4] = make_float4(q00, q01, q02, sp0);
    *(float4*)&lP[((w * 2 + 1) * 32 + l31) * 4] = make_float4(q10, q11, q12, sp1);
  }
  __syncthreads();

  // ---- epilogue: sum the 4 ow waves, add bias, store ----
  {
    int ptL = tid >> 2, ch = tid & 3;
    int pwt = ptL >> 6, pit = (ptL >> 5) & 1, lt = ptL & 31;
    float v = 0.f;
    #pragma unroll
    for (int owt = 0; owt < 4; ++owt) {
      int wv_ = (owt * 2 + pwt);
      v += lP[((wv_ * 2 + pit) * 32 + lt) * 4 + ch];
    }
    v += (ch == 3) ? bfp[0] : bcl[ch];
    out[((size_t)gpt0 + ptL) * 4 + ch] = v;
  }
}

extern "C" void kernel_launch(void* const* d_in, const int* in_sizes, int n_in,
                              void* d_out, int out_size, void* d_ws, size_t ws_size,
                              hipStream_t stream) {
  const float* input = (const float*)d_in[0];
  const float* rdir  = (const float*)d_in[1];
  const float* sn    = (const float*)d_in[2];
  const float* sc    = (const float*)d_in[3];
  const float* W1    = (const float*)d_in[4];
  const float* b1    = (const float*)d_in[5];
  const float* W2    = (const float*)d_in[6];
  const float* b2    = (const float*)d_in[7];
  const float* Wf    = (const float*)d_in[8];
  const float* bf    = (const float*)d_in[9];
  const float* Wcs   = (const float*)d_in[10];
  const float* bcs   = (const float*)d_in[11];
  const float* Wcl   = (const float*)d_in[12];
  const float* bcl   = (const float*)d_in[13];
  unsigned short* wsu = (unsigned short*)d_ws;
  float* out = (float*)d_out;

  prep_w<<<608, 256, 0, stream>>>(W1, W2, Wcs, wsu);
  siren_mfma<<<2048, 512, 0, stream>>>(input, rdir, sn, sc, b1, b2, Wf, bf,
                                       bcs, Wcl, bcl, wsu, out);
}